// Round 1
// baseline (2525.118 us; speedup 1.0000x reference)
//
#include <hip/hip_runtime.h>
#include <cstdint>
#include <cstddef>

#define B_  2048
#define T_  32
#define V_  32000
#define H_  1024
#define A_  1000
#define H3  3072

typedef short short8 __attribute__((ext_vector_type(8)));
typedef float f32x4  __attribute__((ext_vector_type(4)));

typedef __attribute__((address_space(1))) void* as1v;
typedef __attribute__((address_space(3))) void* as3v;

__device__ __forceinline__ unsigned short f2bf(float f) {
  union { float f; unsigned u; } v; v.f = f;
  unsigned r = v.u + 0x7FFFu + ((v.u >> 16) & 1u);   // RNE
  return (unsigned short)(r >> 16);
}

// ---------------------------------------------------------------- converts
__global__ void conv_bf16(const float* __restrict__ src, unsigned short* __restrict__ dst, int n4) {
  int i = blockIdx.x * blockDim.x + threadIdx.x;
  if (i >= n4) return;
  float4 v = ((const float4*)src)[i];
  ushort4 o;
  o.x = f2bf(v.x); o.y = f2bf(v.y); o.z = f2bf(v.z); o.w = f2bf(v.w);
  ((ushort4*)dst)[i] = o;
}

// h1_w [1000,1024] -> padded bf16 [1024,1024] (rows >= 1000 zero)
__global__ void conv_h1w(const float* __restrict__ src, unsigned short* __restrict__ dst) {
  int i = blockIdx.x * blockDim.x + threadIdx.x;
  if (i >= 1024 * 1024) return;
  int row = i >> 10;
  dst[i] = (row < A_) ? f2bf(src[i]) : (unsigned short)0;
}

__global__ void init_state(float* __restrict__ state, unsigned short* __restrict__ hbf) {
  int i = blockIdx.x * blockDim.x + threadIdx.x;
  if (i < B_ * H_) { state[i] = 0.f; hbf[i] = 0; }
}

// alive bitmask per row (bit t = row alive entering step t) + utterance transpose
__global__ void prep(const int* __restrict__ utt, unsigned* __restrict__ alivemask,
                     int* __restrict__ uttT) {
  int b = blockIdx.x * blockDim.x + threadIdx.x;
  if (b >= B_) return;
  unsigned mask = 0, alive = 1;
  #pragma unroll
  for (int t = 0; t < T_; t++) {
    int tk = utt[b * T_ + t];
    mask |= alive << t;
    if (tk == 0) alive = 0;
    uttT[t * B_ + b] = tk;
  }
  alivemask[b] = mask;
}

// ---------------------------------------------------------------- GEMM (m97 pattern)
// C[M,N] = A[M,K] @ W[N,K]^T ; A rows optionally gathered via tok[]
__device__ __forceinline__ void gemm128(
    const unsigned short* __restrict__ Abase,
    const int* __restrict__ tok,          // null -> dense row indexing
    const unsigned short* __restrict__ W,
    float* __restrict__ C,
    int N, int K,
    unsigned short* lA, unsigned short* lB)
{
  const int tid  = threadIdx.x;
  const int lane = tid & 63;
  const int wv   = tid >> 6;
  const int wr   = (wv >> 1) * 64;
  const int wc   = (wv & 1) * 64;
  const int lm   = lane & 15;
  const int lq   = lane >> 4;
  const int bx   = blockIdx.x, by = blockIdx.y;

  f32x4 acc[4][4];
  #pragma unroll
  for (int i = 0; i < 4; i++)
    #pragma unroll
    for (int j = 0; j < 4; j++)
      acc[i][j] = (f32x4){0.f, 0.f, 0.f, 0.f};

  for (int kt = 0; kt < K; kt += 64) {
    __syncthreads();
    #pragma unroll
    for (int r = 0; r < 4; r++) {
      int li  = r * 256 + tid;
      int row = li >> 3;            // 0..127
      int col = (li & 7) << 3;      // 0,8,..,56 (bf16 elems)
      size_t arow = tok ? (size_t)tok[by * 128 + row] : (size_t)(by * 128 + row);
      const unsigned short* ga = Abase + arow * (size_t)K + kt + col;
      __builtin_amdgcn_global_load_lds((as1v)ga, (as3v)(&lA[(size_t)(r * 256 + wv * 64) * 8]), 16, 0, 0);
      const unsigned short* gb = W + (size_t)(bx * 128 + row) * (size_t)K + kt + col;
      __builtin_amdgcn_global_load_lds((as1v)gb, (as3v)(&lB[(size_t)(r * 256 + wv * 64) * 8]), 16, 0, 0);
    }
    __syncthreads();
    #pragma unroll
    for (int kk = 0; kk < 2; kk++) {
      short8 af[4], bf[4];
      #pragma unroll
      for (int i = 0; i < 4; i++)
        af[i] = *(const short8*)&lA[(wr + i * 16 + lm) * 64 + kk * 32 + lq * 8];
      #pragma unroll
      for (int j = 0; j < 4; j++)
        bf[j] = *(const short8*)&lB[(wc + j * 16 + lm) * 64 + kk * 32 + lq * 8];
      #pragma unroll
      for (int i = 0; i < 4; i++)
        #pragma unroll
        for (int j = 0; j < 4; j++)
          acc[i][j] = __builtin_amdgcn_mfma_f32_16x16x32_bf16(af[i], bf[j], acc[i][j], 0, 0, 0);
    }
  }
  // epilogue: C/D layout col=lane&15, row=quad*4+reg  [verified m89/m91]
  #pragma unroll
  for (int i = 0; i < 4; i++) {
    int row0 = by * 128 + wr + i * 16 + lq * 4;
    #pragma unroll
    for (int j = 0; j < 4; j++) {
      int col = bx * 128 + wc + j * 16 + lm;
      #pragma unroll
      for (int rg = 0; rg < 4; rg++)
        C[(size_t)(row0 + rg) * N + col] = acc[i][j][rg];
    }
  }
}

__global__ void __launch_bounds__(256) gemm_step(
    const unsigned short* __restrict__ emb_bf,
    const int* __restrict__ tokcol,
    const unsigned short* __restrict__ wih_bf, float* __restrict__ GI,
    const unsigned short* __restrict__ hbf,
    const unsigned short* __restrict__ whh_bf, float* __restrict__ GH)
{
  __shared__ __align__(16) unsigned short lA[128 * 64];
  __shared__ __align__(16) unsigned short lB[128 * 64];
  if (blockIdx.z == 0) gemm128(emb_bf, tokcol, wih_bf, GI, H3, H_, lA, lB);
  else                 gemm128(hbf, nullptr, whh_bf, GH, H3, H_, lA, lB);
}

__global__ void __launch_bounds__(256) gemm_final(
    const unsigned short* __restrict__ hbf,
    const unsigned short* __restrict__ h1w_bf,
    float* __restrict__ logits)
{
  __shared__ __align__(16) unsigned short lA[128 * 64];
  __shared__ __align__(16) unsigned short lB[128 * 64];
  gemm128(hbf, nullptr, h1w_bf, logits, 1024, H_, lA, lB);
}

// ---------------------------------------------------------------- GRU elementwise
__global__ void gru_update(const float* __restrict__ GI, const float* __restrict__ GH,
                           const float* __restrict__ bih, const float* __restrict__ bhh,
                           float* __restrict__ state, unsigned short* __restrict__ hbf,
                           const unsigned* __restrict__ alivemask, int t)
{
  int idx = blockIdx.x * blockDim.x + threadIdx.x;   // B_*H_ threads
  int b = idx >> 10, j = idx & 1023;
  size_t g0 = (size_t)b * H3 + j;
  float ir = GI[g0]          + bih[j];
  float iz = GI[g0 + H_]     + bih[H_ + j];
  float in_= GI[g0 + 2 * H_] + bih[2 * H_ + j];
  float hr = GH[g0]          + bhh[j];
  float hz = GH[g0 + H_]     + bhh[H_ + j];
  float hn = GH[g0 + 2 * H_] + bhh[2 * H_ + j];
  float r = 1.f / (1.f + expf(-(ir + hr)));
  float z = 1.f / (1.f + expf(-(iz + hz)));
  float n = tanhf(in_ + r * hn);
  float h = state[idx];
  float nh = (1.f - z) * n + z * h;
  float o = ((alivemask[b] >> t) & 1u) ? nh : h;
  state[idx] = o;
  hbf[idx] = f2bf(o);
}

// ---------------------------------------------------------------- softmax head
__global__ void __launch_bounds__(256) softmax_k(const float* __restrict__ logits,
                                                 const float* __restrict__ h1b,
                                                 float* __restrict__ out)
{
  int b = blockIdx.x;
  int tid = threadIdx.x;
  __shared__ float red[8];
  float v[4];
  float lmax = -3.4e38f;
  #pragma unroll
  for (int k = 0; k < 4; k++) {
    int j = tid + k * 256;
    float x = (j < A_) ? (logits[(size_t)b * 1024 + j] + h1b[j]) : -3.4e38f;
    v[k] = x;
    lmax = fmaxf(lmax, x);
  }
  #pragma unroll
  for (int off = 1; off < 64; off <<= 1) lmax = fmaxf(lmax, __shfl_xor(lmax, off, 64));
  if ((tid & 63) == 0) red[tid >> 6] = lmax;
  __syncthreads();
  lmax = fmaxf(fmaxf(red[0], red[1]), fmaxf(red[2], red[3]));
  float s = 0.f;
  #pragma unroll
  for (int k = 0; k < 4; k++) {
    int j = tid + k * 256;
    float e = (j < A_) ? expf(v[k] - lmax) : 0.f;
    v[k] = e; s += e;
  }
  #pragma unroll
  for (int off = 1; off < 64; off <<= 1) s += __shfl_xor(s, off, 64);
  if ((tid & 63) == 0) red[4 + (tid >> 6)] = s;
  __syncthreads();
  s = red[4] + red[5] + red[6] + red[7];
  float inv = 1.f / s;
  #pragma unroll
  for (int k = 0; k < 4; k++) {
    int j = tid + k * 256;
    if (j < A_) out[(size_t)b * A_ + j] = v[k] * inv;
  }
}

// ---------------------------------------------------------------- launch
extern "C" void kernel_launch(void* const* d_in, const int* in_sizes, int n_in,
                              void* d_out, int out_size, void* d_ws, size_t ws_size,
                              hipStream_t stream)
{
  (void)in_sizes; (void)n_in; (void)out_size; (void)ws_size;
  const int*   utt   = (const int*)d_in[0];
  // d_in[1] global_idxes: unused by reference
  const float* emb_w = (const float*)d_in[2];
  const float* w_ih  = (const float*)d_in[3];
  const float* w_hh  = (const float*)d_in[4];
  const float* b_ih  = (const float*)d_in[5];
  const float* b_hh  = (const float*)d_in[6];
  const float* h1_w  = (const float*)d_in[7];
  const float* h1_b  = (const float*)d_in[8];
  float* out = (float*)d_out;

  char* ws = (char*)d_ws;
  size_t off = 0;
  auto alloc = [&](size_t bytes) {
    void* p = ws + off;
    off += (bytes + 255) & ~(size_t)255;
    return p;
  };
  unsigned short* emb_bf = (unsigned short*)alloc((size_t)V_ * H_ * 2);   // 65.5 MB
  unsigned short* wih_bf = (unsigned short*)alloc((size_t)H3 * H_ * 2);   // 6.3 MB
  unsigned short* whh_bf = (unsigned short*)alloc((size_t)H3 * H_ * 2);   // 6.3 MB
  unsigned short* h1w_bf = (unsigned short*)alloc((size_t)1024 * H_ * 2); // 2.1 MB
  float*          GI     = (float*)alloc((size_t)B_ * H3 * 4);            // 25.2 MB
  float*          GH     = (float*)alloc((size_t)B_ * H3 * 4);            // 25.2 MB
  float*          state  = (float*)alloc((size_t)B_ * H_ * 4);            // 8.4 MB
  unsigned short* hbf    = (unsigned short*)alloc((size_t)B_ * H_ * 2);   // 4.2 MB
  float*          logits = (float*)alloc((size_t)B_ * 1024 * 4);          // 8.4 MB
  int*            uttT   = (int*)alloc((size_t)B_ * T_ * 4);
  unsigned*       amask  = (unsigned*)alloc((size_t)B_ * 4);

  int n4 = V_ * H_ / 4;
  conv_bf16<<<(n4 + 255) / 256, 256, 0, stream>>>(emb_w, emb_bf, n4);
  n4 = H3 * H_ / 4;
  conv_bf16<<<(n4 + 255) / 256, 256, 0, stream>>>(w_ih, wih_bf, n4);
  conv_bf16<<<(n4 + 255) / 256, 256, 0, stream>>>(w_hh, whh_bf, n4);
  conv_h1w<<<(1024 * 1024) / 256, 256, 0, stream>>>(h1_w, h1w_bf);
  init_state<<<(B_ * H_) / 256, 256, 0, stream>>>(state, hbf);
  prep<<<(B_ + 255) / 256, 256, 0, stream>>>(utt, amask, uttT);

  dim3 gs(H3 / 128, B_ / 128, 2);   // 24 x 16 x 2
  for (int t = 0; t < T_; t++) {
    gemm_step<<<gs, 256, 0, stream>>>(emb_bf, uttT + (size_t)t * B_, wih_bf, GI, hbf, whh_bf, GH);
    gru_update<<<(B_ * H_) / 256, 256, 0, stream>>>(GI, GH, b_ih, b_hh, state, hbf, amask, t);
  }
  dim3 gf(1024 / 128, B_ / 128, 1); // 8 x 16
  gemm_final<<<gf, 256, 0, stream>>>(hbf, h1w_bf, logits);
  softmax_k<<<B_, 256, 0, stream>>>(logits, h1_b, out);
}